// Round 6
// baseline (6587.351 us; speedup 1.0000x reference)
//
#include <hip/hip_runtime.h>
#include <hip/hip_bf16.h>
#include <stdint.h>

// Problem dims
#define NB 512
#define NT 20
#define NH 256
#define NSD 64
#define NO 128

// ===== LEDGER =====
//  R1-R4: FAIL ~19 — ALL VOID: d_out was written as bf16 but harness reads f32.
//  R5 probe: 18.816 not in any designed band -> decoded: out dtype = FLOAT32.
//    (bf16 64.0 at bf16-idx128 vanished into f32 mantissa; chunk0 2nd half = odd
//     x-copy values -> 18.816 = max|x - ref_xrecon|. All consistent.)
//  R6 (this): f32 stores + partitionable PRNG (foldlike split, bits = o0^o1).
//  Fallback if FAIL~19: legacy split+pairing (R2 mapping) in f32.
// ==================

__host__ __device__ __forceinline__ void tf2x32(uint32_t k0, uint32_t k1,
                                                uint32_t x0, uint32_t x1,
                                                uint32_t& o0, uint32_t& o1)
{
  uint32_t k2 = k0 ^ k1 ^ 0x1BD11BDAu;
  x0 += k0; x1 += k1;
#define TF_R(r) x0 += x1; x1 = (x1 << (r)) | (x1 >> (32 - (r))); x1 ^= x0;
  TF_R(13) TF_R(15) TF_R(26) TF_R(6)
  x0 += k1; x1 += k2 + 1u;
  TF_R(17) TF_R(29) TF_R(16) TF_R(24)
  x0 += k2; x1 += k0 + 2u;
  TF_R(13) TF_R(15) TF_R(26) TF_R(6)
  x0 += k0; x1 += k1 + 3u;
  TF_R(17) TF_R(29) TF_R(16) TF_R(24)
  x0 += k1; x1 += k2 + 4u;
  TF_R(13) TF_R(15) TF_R(26) TF_R(6)
  x0 += k2; x1 += k0 + 5u;
#undef TF_R
  o0 = x0; o1 = x1;
}

// partitionable 32-bit random_bits: cipher(key, (0,i)) -> bits1 ^ bits2
__device__ __forceinline__ uint32_t rbits(uint32_t ka, uint32_t kb, uint32_t i)
{
  uint32_t o0, o1;
  tf2x32(ka, kb, 0u, i, o0, o1);
  return o0 ^ o1;
}

// XLA ErfInv32 (Giles) — exact coefficient match, no FMA contraction.
__device__ __forceinline__ float erfinv_xla(float x)
{
  float w = -log1pf(-__fmul_rn(x, x));
  float p;
  if (w < 5.0f) {
    w = __fsub_rn(w, 2.5f);
    p = 2.81022636e-08f;
    p = __fadd_rn( 3.43273939e-07f, __fmul_rn(p, w));
    p = __fadd_rn(-3.5233877e-06f,  __fmul_rn(p, w));
    p = __fadd_rn(-4.39150654e-06f, __fmul_rn(p, w));
    p = __fadd_rn( 0.00021858087f,  __fmul_rn(p, w));
    p = __fadd_rn(-0.00125372503f,  __fmul_rn(p, w));
    p = __fadd_rn(-0.00417768164f,  __fmul_rn(p, w));
    p = __fadd_rn( 0.246640727f,    __fmul_rn(p, w));
    p = __fadd_rn( 1.50140941f,     __fmul_rn(p, w));
  } else {
    w = __fsub_rn(sqrtf(w), 3.0f);
    p = -0.000200214257f;
    p = __fadd_rn( 0.000100950558f, __fmul_rn(p, w));
    p = __fadd_rn( 0.00134934322f,  __fmul_rn(p, w));
    p = __fadd_rn(-0.00367342844f,  __fmul_rn(p, w));
    p = __fadd_rn( 0.00573950773f,  __fmul_rn(p, w));
    p = __fadd_rn(-0.0076224613f,   __fmul_rn(p, w));
    p = __fadd_rn( 0.00943887047f,  __fmul_rn(p, w));
    p = __fadd_rn( 1.00167406f,     __fmul_rn(p, w));
    p = __fadd_rn( 2.83297682f,     __fmul_rn(p, w));
  }
  return __fmul_rn(p, x);
}

// jax.random.normal(f32): uniform in [nextafter(-1,0), 1) then sqrt(2)*erfinv
__device__ __forceinline__ float jax_normal(uint32_t bits)
{
  float f = __fsub_rn(__uint_as_float((bits >> 9) | 0x3F800000u), 1.0f);
  const float lo = -0.99999994f;
  float u = __fadd_rn(__fmul_rn(f, 2.0f), lo); // (1 - lo) rounds to 2.0f
  u = fmaxf(lo, u);
  return __fmul_rn(1.41421356f, erfinv_xla(u));
}

// ---------------- kernels ----------------

// out layout (f32): [x_recon 512*20*128 | x 512*20*128 | mu 512*20*256 | var 512*20*256]
__global__ void k_init_x(const float* __restrict__ x, float* __restrict__ out)
{
  int i = blockIdx.x * blockDim.x + threadIdx.x;
  const int total = NB * NT * NO;
  if (i >= total) return;
  float v = x[i];
  out[total + i] = v;                    // x passthrough (bit-exact)
  if ((i % (NT * NO)) < NO) out[i] = v;  // x_recon[:,0,:] = x[:,0,:]
}

__global__ void k_init_h(const float* __restrict__ mu0, const float* __restrict__ var0,
                         const float* __restrict__ h0,
                         float* __restrict__ out, float* __restrict__ hstate)
{
  int i = blockIdx.x * blockDim.x + threadIdx.x;
  if (i >= NB * NH) return;
  int b = i >> 8, h = i & 255;
  const int MUO = 2 * NB * NT * NO;
  const int VARO = MUO + NB * NT * NH;
  out[MUO  + (b * NT) * NH + h] = mu0[h];
  out[VARO + (b * NT) * NH + h] = var0[h];
  hstate[i] = h0[h];
}

// out[b,o] = relu( dot(xin[b,:256], W[o,:256]) + bias[o] ), 512 outputs
__global__ void k_gemm_relu256(const float* __restrict__ xin, const float* __restrict__ W,
                               const float* __restrict__ bias, float* __restrict__ out)
{
  int b = blockIdx.x;
  __shared__ float xs[256];
  if (threadIdx.x < 256) xs[threadIdx.x] = xin[b * 256 + threadIdx.x];
  __syncthreads();
  for (int o = threadIdx.x; o < 512; o += 256) {
    const float* w = W + o * 256;
    float acc = bias[o];
    for (int k = 0; k < 256; k += 4) {
      float4 wv = *reinterpret_cast<const float4*>(w + k);
      acc += xs[k] * wv.x + xs[k+1] * wv.y + xs[k+2] * wv.z + xs[k+3] * wv.w;
    }
    out[b * 512 + o] = fmaxf(acc, 0.0f);
  }
}

// per-channel BN stats over batch -> scale/shift
__global__ void k_bnstat(const float* __restrict__ x, int C,
                         const float* __restrict__ g, const float* __restrict__ be,
                         float* __restrict__ sc, float* __restrict__ sh)
{
  int c = blockIdx.x;
  int l = threadIdx.x; // 64 = one wave
  float s = 0.0f;
  for (int b = l; b < NB; b += 64) s += x[b * C + c];
  for (int off = 32; off; off >>= 1) s += __shfl_xor(s, off);
  float m = s * (1.0f / NB);
  float v = 0.0f;
  for (int b = l; b < NB; b += 64) { float d = x[b * C + c] - m; v += d * d; }
  for (int off = 32; off; off >>= 1) v += __shfl_xor(v, off);
  if (l == 0) {
    float var = v * (1.0f / NB);
    float inv = 1.0f / sqrtf(var + 1e-5f);
    float scale = inv * g[c];
    sc[c] = scale;
    sh[c] = be[c] - m * scale;
  }
}

// a2[b,o] = relu( dot([bn(a1[b,:]), s[b,:]], W2[o,:576]) + b2[o] )
__global__ void k_gemm2(const float* __restrict__ a1, const float* __restrict__ sc1,
                        const float* __restrict__ sh1, const float* __restrict__ sb,
                        const float* __restrict__ W2, const float* __restrict__ b2,
                        float* __restrict__ a2)
{
  int b = blockIdx.x;
  __shared__ float xs[576];
  for (int i = threadIdx.x; i < 512; i += 256) xs[i] = a1[b * 512 + i] * sc1[i] + sh1[i];
  if (threadIdx.x < NSD) xs[512 + threadIdx.x] = sb[b * NSD + threadIdx.x];
  __syncthreads();
  for (int o = threadIdx.x; o < 512; o += 256) {
    const float* w = W2 + o * 576;
    float acc = b2[o];
    for (int k = 0; k < 576; k += 4) {
      float4 wv = *reinterpret_cast<const float4*>(w + k);
      acc += xs[k] * wv.x + xs[k+1] * wv.y + xs[k+2] * wv.z + xs[k+3] * wv.w;
    }
    a2[b * 512 + o] = fmaxf(acc, 0.0f);
  }
}

// mu (write table + f32 out) and pre-BN sd
__global__ void k_musd(const float* __restrict__ a2, const float* __restrict__ sc2,
                       const float* __restrict__ sh2,
                       const float* __restrict__ Wm, const float* __restrict__ bm,
                       const float* __restrict__ Ws, const float* __restrict__ bs,
                       float* __restrict__ muT, float* __restrict__ ps,
                       float* __restrict__ out, int t)
{
  int b = blockIdx.x;
  __shared__ float xs[512];
  for (int i = threadIdx.x; i < 512; i += 256) xs[i] = a2[b * 512 + i] * sc2[i] + sh2[i];
  __syncthreads();
  int h = threadIdx.x; // 256 threads
  const float* wm = Wm + h * 512;
  const float* wsp = Ws + h * 512;
  float am = bm[h], as = bs[h];
  for (int k = 0; k < 512; k += 4) {
    float4 wv = *reinterpret_cast<const float4*>(wm + k);
    am += xs[k] * wv.x + xs[k+1] * wv.y + xs[k+2] * wv.z + xs[k+3] * wv.w;
    float4 sv = *reinterpret_cast<const float4*>(wsp + k);
    as += xs[k] * sv.x + xs[k+1] * sv.y + xs[k+2] * sv.z + xs[k+3] * sv.w;
  }
  muT[((t - 1) * NB + b) * NH + h] = am;
  const int MUO = 2 * NB * NT * NO;
  out[MUO + (b * NT + t) * NH + h] = am;
  float e = as > 0.0f ? as : expm1f(as);
  ps[b * NH + h] = (e + 1.0f) + 1e-12f;
}

__global__ void k_varwrite(const float* __restrict__ ps, const float* __restrict__ scS,
                           const float* __restrict__ shS, float* __restrict__ sdT,
                           float* __restrict__ out, int t)
{
  int i = blockIdx.x * blockDim.x + threadIdx.x;
  if (i >= NB * NH) return;
  int b = i >> 8, h = i & 255;
  float v = ps[i] * scS[h] + shS[h];
  sdT[((t - 1) * NB + b) * NH + h] = v;
  const int VARO = 2 * NB * NT * NO + NB * NT * NH;
  out[VARO + (b * NT + t) * NH + h] = v;
}

// categorical: Gumbel argmax over u<t (first-index tie-break)
__global__ void k_pis(const float* __restrict__ h_gru, int t,
                      uint32_t ka, uint32_t kb, int* __restrict__ pis)
{
  int b = blockIdx.x;
  int l = threadIdx.x; // 64 = one wave
  float v = -__builtin_inff();
  int idx = 0x7FFFFFFF;
  if (l < t) {
    const float* hq = h_gru + (b * NT + t) * NH;
    const float* hu = h_gru + (b * NT + l) * NH;
    float d = 0.0f;
    for (int h = 0; h < NH; ++h) d += hq[h] * hu[h];
    float logit = d * 0.0625f; // / sqrt(256)
    uint32_t bits = rbits(ka, kb, (uint32_t)(b * t + l));
    float f = __fsub_rn(__uint_as_float((bits >> 9) | 0x3F800000u), 1.0f);
    const float tinyf = 1.1754943508222875e-38f;
    float u = fmaxf(tinyf, __fadd_rn(f, tinyf));
    float gmb = -logf(-logf(u));
    v = gmb + logit;
    idx = l;
  }
  for (int off = 32; off; off >>= 1) {
    float ov = __shfl_xor(v, off);
    int oi = __shfl_xor(idx, off);
    if (ov > v || (ov == v && oi < idx)) { v = ov; idx = oi; }
  }
  if (l == 0) pis[b] = idx;
}

// ht = mu[pis] + sd[pis] * N(0,1)
__global__ void k_ht(const float* __restrict__ muT, const float* __restrict__ sdT,
                     const int* __restrict__ pis, uint32_t ka, uint32_t kb,
                     float* __restrict__ hstate)
{
  int i = blockIdx.x * blockDim.x + threadIdx.x;
  if (i >= NB * NH) return;
  int b = i >> 8, h = i & 255;
  int p = pis[b];
  float mu = muT[(p * NB + b) * NH + h];
  float sd = sdT[(p * NB + b) * NH + h];
  float z = jax_normal(rbits(ka, kb, (uint32_t)i));
  hstate[i] = __fadd_rn(mu, __fmul_rn(sd, z));
}

// emission output: mean + std * N(0,1), store f32
__global__ void k_eout(const float* __restrict__ e1, const float* __restrict__ scE,
                       const float* __restrict__ shE,
                       const float* __restrict__ Wm, const float* __restrict__ bm,
                       const float* __restrict__ Ws, const float* __restrict__ bs,
                       uint32_t ka, uint32_t kb, float* __restrict__ out, int t)
{
  int b = blockIdx.x;
  __shared__ float xs[512];
  for (int i = threadIdx.x; i < 512; i += 128) xs[i] = e1[b * 512 + i] * scE[i] + shE[i];
  __syncthreads();
  int j = threadIdx.x; // 128 threads
  const float* wm = Wm + j * 512;
  const float* wsp = Ws + j * 512;
  float am = bm[j], as = bs[j];
  for (int k = 0; k < 512; k += 4) {
    float4 wv = *reinterpret_cast<const float4*>(wm + k);
    am += xs[k] * wv.x + xs[k+1] * wv.y + xs[k+2] * wv.z + xs[k+3] * wv.w;
    float4 sv = *reinterpret_cast<const float4*>(wsp + k);
    as += xs[k] * sv.x + xs[k+1] * sv.y + xs[k+2] * sv.z + xs[k+3] * sv.w;
  }
  float e = as > 0.0f ? as : expm1f(as);
  float stdv = (e + 1.0f) + 1e-12f;
  float z = jax_normal(rbits(ka, kb, (uint32_t)(b * NO + j)));
  out[(b * NT + t) * NO + j] = __fadd_rn(am, __fmul_rn(stdv, z));
}

// ---------------- host ----------------

extern "C" void kernel_launch(void* const* d_in, const int* in_sizes, int n_in,
                              void* d_out, int out_size, void* d_ws, size_t ws_size,
                              hipStream_t stream)
{
  const float* x     = (const float*)d_in[0];
  const float* s     = (const float*)d_in[1];
  const float* h_gru = (const float*)d_in[2];
  const float* mu0   = (const float*)d_in[3];
  const float* var0  = (const float*)d_in[4];
  const float* h0    = (const float*)d_in[5];
  const float* tW1   = (const float*)d_in[6];
  const float* tb1   = (const float*)d_in[7];
  const float* tg1   = (const float*)d_in[8];
  const float* tbe1  = (const float*)d_in[9];
  const float* tW2   = (const float*)d_in[10];
  const float* tb2   = (const float*)d_in[11];
  const float* tg2   = (const float*)d_in[12];
  const float* tbe2  = (const float*)d_in[13];
  const float* tWm   = (const float*)d_in[14];
  const float* tbm   = (const float*)d_in[15];
  const float* tWs   = (const float*)d_in[16];
  const float* tbs   = (const float*)d_in[17];
  const float* tgs   = (const float*)d_in[18];
  const float* tbes  = (const float*)d_in[19];
  const float* eW1   = (const float*)d_in[20];
  const float* eb1   = (const float*)d_in[21];
  const float* eg1   = (const float*)d_in[22];
  const float* ebe1  = (const float*)d_in[23];
  const float* eWm   = (const float*)d_in[24];
  const float* ebm   = (const float*)d_in[25];
  const float* eWs   = (const float*)d_in[26];
  const float* ebs   = (const float*)d_in[27];

  float* out = (float*)d_out;
  float* ws = (float*)d_ws;

  float* muT    = ws;                      // 19*NB*NH
  float* sdT    = muT + 19 * NB * NH;      // 19*NB*NH
  float* hstate = sdT + 19 * NB * NH;      // NB*NH
  float* a1     = hstate + NB * NH;        // NB*512
  float* a2     = a1 + NB * 512;           // NB*512
  float* ps     = a2 + NB * 512;           // NB*NH
  float* e1     = ps + NB * NH;            // NB*512
  float* sc1 = e1 + NB * 512;  float* sh1 = sc1 + 512;
  float* sc2 = sh1 + 512;      float* sh2 = sc2 + 512;
  float* scS = sh2 + 512;      float* shS = scS + 256;
  float* scE = shS + 256;      float* shE = scE + 512;
  int*   pis = (int*)(shE + 512);

  k_init_x<<<(NB * NT * NO + 255) / 256, 256, 0, stream>>>(x, out);
  k_init_h<<<(NB * NH + 255) / 256, 256, 0, stream>>>(mu0, var0, h0, out, hstate);

  for (int t = 1; t < NT; ++t) {
    uint32_t kt0, kt1;
    tf2x32(0u, 42u, 0u, (uint32_t)t, kt0, kt1);        // fold_in(key(42), t)
    uint32_t k1a, k1b, k2a, k2b, k3a, k3b;
    // partitionable (foldlike) split: subkey i = full cipher(key, (0, i))
    tf2x32(kt0, kt1, 0u, 0u, k1a, k1b);
    tf2x32(kt0, kt1, 0u, 1u, k2a, k2b);
    tf2x32(kt0, kt1, 0u, 2u, k3a, k3b);

    // transition for timestep u = t-1 (incremental; BN is per-(timestep,channel)
    // over batch, so per-step recompute is exact)
    k_gemm_relu256<<<NB, 256, 0, stream>>>(hstate, tW1, tb1, a1);
    k_bnstat<<<512, 64, 0, stream>>>(a1, 512, tg1, tbe1, sc1, sh1);
    k_gemm2<<<NB, 256, 0, stream>>>(a1, sc1, sh1, s, tW2, tb2, a2);
    k_bnstat<<<512, 64, 0, stream>>>(a2, 512, tg2, tbe2, sc2, sh2);
    k_musd<<<NB, 256, 0, stream>>>(a2, sc2, sh2, tWm, tbm, tWs, tbs, muT, ps, out, t);
    k_bnstat<<<256, 64, 0, stream>>>(ps, 256, tgs, tbes, scS, shS);
    k_varwrite<<<(NB * NH + 255) / 256, 256, 0, stream>>>(ps, scS, shS, sdT, out, t);
    // sampling
    k_pis<<<NB, 64, 0, stream>>>(h_gru, t, k1a, k1b, pis);
    k_ht<<<(NB * NH + 255) / 256, 256, 0, stream>>>(muT, sdT, pis, k2a, k2b, hstate);
    // emission
    k_gemm_relu256<<<NB, 256, 0, stream>>>(hstate, eW1, eb1, e1);
    k_bnstat<<<512, 64, 0, stream>>>(e1, 512, eg1, ebe1, scE, shE);
    k_eout<<<NB, 128, 0, stream>>>(e1, scE, shE, eWm, ebm, eWs, ebs, k3a, k3b, out, t);
  }
}

// Round 7
// 1557.299 us; speedup vs baseline: 4.2300x; 4.2300x over previous
//
#include <hip/hip_runtime.h>
#include <hip/hip_bf16.h>
#include <stdint.h>

#define NB 512
#define NT 20
#define NH 256
#define NSD 64
#define NO 128
#define MUO_OFF (2*NB*NT*NO)
#define VARO_OFF (MUO_OFF + NB*NT*NH)

// ===== LEDGER =====
//  R1-R5: PRNG hunts were chasing a dtype bug; R5 probe decoded out dtype = f32.
//  R6: PASS. 6587us. k_musd 89.5us x19, VALUBusy 5.5%, HBM 0.9% -> latency/L2-bound
//      serial-dot GEMMs. PRNG: partitionable foldlike split, bits = o0^o1.
//  R7 (this): tiled dbuf LDS GEMMs + fused BN prologue/epilogue + fused small
//      kernels. 154 launches. Target ~1000-1600us.
// ==================

__host__ __device__ __forceinline__ void tf2x32(uint32_t k0, uint32_t k1,
                                                uint32_t x0, uint32_t x1,
                                                uint32_t& o0, uint32_t& o1)
{
  uint32_t k2 = k0 ^ k1 ^ 0x1BD11BDAu;
  x0 += k0; x1 += k1;
#define TF_R(r) x0 += x1; x1 = (x1 << (r)) | (x1 >> (32 - (r))); x1 ^= x0;
  TF_R(13) TF_R(15) TF_R(26) TF_R(6)
  x0 += k1; x1 += k2 + 1u;
  TF_R(17) TF_R(29) TF_R(16) TF_R(24)
  x0 += k2; x1 += k0 + 2u;
  TF_R(13) TF_R(15) TF_R(26) TF_R(6)
  x0 += k0; x1 += k1 + 3u;
  TF_R(17) TF_R(29) TF_R(16) TF_R(24)
  x0 += k1; x1 += k2 + 4u;
  TF_R(13) TF_R(15) TF_R(26) TF_R(6)
  x0 += k2; x1 += k0 + 5u;
#undef TF_R
  o0 = x0; o1 = x1;
}

__device__ __forceinline__ uint32_t rbits(uint32_t ka, uint32_t kb, uint32_t i)
{
  uint32_t o0, o1;
  tf2x32(ka, kb, 0u, i, o0, o1);
  return o0 ^ o1;
}

__device__ __forceinline__ float erfinv_xla(float x)
{
  float w = -log1pf(-__fmul_rn(x, x));
  float p;
  if (w < 5.0f) {
    w = __fsub_rn(w, 2.5f);
    p = 2.81022636e-08f;
    p = __fadd_rn( 3.43273939e-07f, __fmul_rn(p, w));
    p = __fadd_rn(-3.5233877e-06f,  __fmul_rn(p, w));
    p = __fadd_rn(-4.39150654e-06f, __fmul_rn(p, w));
    p = __fadd_rn( 0.00021858087f,  __fmul_rn(p, w));
    p = __fadd_rn(-0.00125372503f,  __fmul_rn(p, w));
    p = __fadd_rn(-0.00417768164f,  __fmul_rn(p, w));
    p = __fadd_rn( 0.246640727f,    __fmul_rn(p, w));
    p = __fadd_rn( 1.50140941f,     __fmul_rn(p, w));
  } else {
    w = __fsub_rn(sqrtf(w), 3.0f);
    p = -0.000200214257f;
    p = __fadd_rn( 0.000100950558f, __fmul_rn(p, w));
    p = __fadd_rn( 0.00134934322f,  __fmul_rn(p, w));
    p = __fadd_rn(-0.00367342844f,  __fmul_rn(p, w));
    p = __fadd_rn( 0.00573950773f,  __fmul_rn(p, w));
    p = __fadd_rn(-0.0076224613f,   __fmul_rn(p, w));
    p = __fadd_rn( 0.00943887047f,  __fmul_rn(p, w));
    p = __fadd_rn( 1.00167406f,     __fmul_rn(p, w));
    p = __fadd_rn( 2.83297682f,     __fmul_rn(p, w));
  }
  return __fmul_rn(p, x);
}

__device__ __forceinline__ float jax_normal(uint32_t bits)
{
  float f = __fsub_rn(__uint_as_float((bits >> 9) | 0x3F800000u), 1.0f);
  const float lo = -0.99999994f;
  float u = __fadd_rn(__fmul_rn(f, 2.0f), lo);
  u = fmaxf(lo, u);
  return __fmul_rn(1.41421356f, erfinv_xla(u));
}

// ---------------- init kernels ----------------

__global__ void k_init_x(const float* __restrict__ x, float* __restrict__ out)
{
  int i = blockIdx.x * blockDim.x + threadIdx.x;
  const int total = NB * NT * NO;
  if (i >= total) return;
  float v = x[i];
  out[total + i] = v;
  if ((i % (NT * NO)) < NO) out[i] = v;
}

__global__ void k_init_h(const float* __restrict__ mu0, const float* __restrict__ var0,
                         const float* __restrict__ h0,
                         float* __restrict__ out, float* __restrict__ hstate)
{
  int i = blockIdx.x * blockDim.x + threadIdx.x;
  if (i >= NB * NH) return;
  int b = i >> 8, h = i & 255;
  out[MUO_OFF  + (b * NT) * NH + h] = mu0[h];
  out[VARO_OFF + (b * NT) * NH + h] = var0[h];
  hstate[i] = h0[h];
}

// ---------------- tiled GEMM ----------------
// C[m][n] = sum_k A[m][k] * W[n][k]  (both row-major, K contiguous)
// BM=BN=32, BK=32, 256 threads, 2x2 per thread, double-buffered LDS.
// BNA: apply BN to A on load (sc/sh built from partIn in prologue).
// CONC: A = [bn(a1) | s] (K=576, split at 512).
// EPI 0: relu + C write + stats partials (sum, sumsq per column per m-block)
// EPI 1: musd — n<256: mu -> muT + out; n>=256: elu+1+eps -> ps + stats partials
// EPI 2: eout — n<128: mean; n>=128: elu+1+eps -> tmp (no stats)
template<int KTOT, int BNA, int CONC, int EPI>
__global__ __launch_bounds__(256) void k_gemm(
    const float* __restrict__ A, const float* __restrict__ S,
    const float* __restrict__ partIn, const float* __restrict__ g,
    const float* __restrict__ be,
    const float* __restrict__ W0, const float* __restrict__ W1,
    const float* __restrict__ b0, const float* __restrict__ b1,
    float* __restrict__ Cout, float* __restrict__ partOut,
    float* __restrict__ muT, float* __restrict__ outp, int t)
{
  constexpr int NS = KTOT / 32;
  constexpr int AST = CONC ? 512 : KTOT;   // A row stride
  const int tid = threadIdx.x;
  const int tx = tid & 15, ty = tid >> 4;
  const int n0 = blockIdx.x * 32, m0 = blockIdx.y * 32;
  const int kq = tid & 7, lrow = tid >> 3;   // loader mapping: 8 kq x 32 rows

  __shared__ float As[2][32][34];
  __shared__ float Bs[2][32][34];
  __shared__ float redS[4][32], redQ[4][32];
  __shared__ float scs[BNA ? 512 : 1], shs[BNA ? 512 : 1];

  if constexpr (BNA) {
    for (int c = tid; c < 512; c += 256) {
      float s = 0.0f, q = 0.0f;
      #pragma unroll
      for (int p = 0; p < 16; ++p) {
        s += partIn[(p * 512 + c) * 2];
        q += partIn[(p * 512 + c) * 2 + 1];
      }
      float mn  = s * (1.0f / 512.0f);
      float var = q * (1.0f / 512.0f) - mn * mn;
      float inv = 1.0f / sqrtf(var + 1e-5f);
      float sc  = inv * g[c];
      scs[c] = sc;
      shs[c] = be[c] - mn * sc;
    }
    __syncthreads();
  }

  float4 av, bv;

  auto LOADK = [&](int s) {
    const int k0 = s * 32;
    const int kk = k0 + kq * 4;
    const float* ap;
    if constexpr (CONC) {
      ap = (k0 >= 512) ? (S + (m0 + lrow) * NSD + (kk - 512))
                       : (A + (m0 + lrow) * AST + kk);
    } else {
      ap = A + (m0 + lrow) * AST + kk;
    }
    av = *reinterpret_cast<const float4*>(ap);
    const int n = n0 + lrow;
    const float* wp;
    if constexpr (EPI == 1)      wp = (n0 < 256) ? (W0 + n * KTOT) : (W1 + (n - 256) * KTOT);
    else if constexpr (EPI == 2) wp = (n0 < 128) ? (W0 + n * KTOT) : (W1 + (n - 128) * KTOT);
    else                         wp = W0 + n * KTOT;
    bv = *reinterpret_cast<const float4*>(wp + kk);
  };

  auto WRITEK = [&](int s, int buf) {
    const int k0 = s * 32;
    float4 v = av;
    if constexpr (BNA) {
      if (!CONC || k0 < 512) {
        const int kb = k0 + kq * 4;
        v.x = v.x * scs[kb]     + shs[kb];
        v.y = v.y * scs[kb + 1] + shs[kb + 1];
        v.z = v.z * scs[kb + 2] + shs[kb + 2];
        v.w = v.w * scs[kb + 3] + shs[kb + 3];
      }
    }
    const int r = kq * 4;
    As[buf][r][lrow]     = v.x;
    As[buf][r + 1][lrow] = v.y;
    As[buf][r + 2][lrow] = v.z;
    As[buf][r + 3][lrow] = v.w;
    Bs[buf][r][lrow]     = bv.x;
    Bs[buf][r + 1][lrow] = bv.y;
    Bs[buf][r + 2][lrow] = bv.z;
    Bs[buf][r + 3][lrow] = bv.w;
  };

  float acc00 = 0.0f, acc01 = 0.0f, acc10 = 0.0f, acc11 = 0.0f;

  auto COMP = [&](int buf) {
    #pragma unroll
    for (int kk = 0; kk < 32; ++kk) {
      float2 a = *reinterpret_cast<const float2*>(&As[buf][kk][2 * ty]);
      float2 b = *reinterpret_cast<const float2*>(&Bs[buf][kk][2 * tx]);
      acc00 = __builtin_fmaf(a.x, b.x, acc00);
      acc01 = __builtin_fmaf(a.x, b.y, acc01);
      acc10 = __builtin_fmaf(a.y, b.x, acc10);
      acc11 = __builtin_fmaf(a.y, b.y, acc11);
    }
  };

  LOADK(0);
  WRITEK(0, 0);
  __syncthreads();
  for (int s = 0; s < NS; ++s) {
    const int c = s & 1;
    if (s + 1 < NS) LOADK(s + 1);
    COMP(c);
    __syncthreads();
    if (s + 1 < NS) { WRITEK(s + 1, 1 - c); __syncthreads(); }
  }

  const int mA = m0 + 2 * ty;
  const int nA = n0 + 2 * tx;

  auto STATS = [&](float v00, float v01, float v10, float v11, int nbase, int cch) {
    float s0 = v00 + v10, s1 = v01 + v11;
    float q0 = v00 * v00 + v10 * v10, q1 = v01 * v01 + v11 * v11;
    s0 += __shfl_xor(s0, 16); s0 += __shfl_xor(s0, 32);
    s1 += __shfl_xor(s1, 16); s1 += __shfl_xor(s1, 32);
    q0 += __shfl_xor(q0, 16); q0 += __shfl_xor(q0, 32);
    q1 += __shfl_xor(q1, 16); q1 += __shfl_xor(q1, 32);
    if ((tid & 63) < 16) {
      int w = tid >> 6;
      redS[w][2 * tx] = s0; redS[w][2 * tx + 1] = s1;
      redQ[w][2 * tx] = q0; redQ[w][2 * tx + 1] = q1;
    }
    __syncthreads();
    if (tid < 32) {
      float Sv = redS[0][tid] + redS[1][tid] + redS[2][tid] + redS[3][tid];
      float Qv = redQ[0][tid] + redQ[1][tid] + redQ[2][tid] + redQ[3][tid];
      int nglob = nbase + tid;
      partOut[((int)blockIdx.y * cch + nglob) * 2]     = Sv;
      partOut[((int)blockIdx.y * cch + nglob) * 2 + 1] = Qv;
    }
  };

  if constexpr (EPI == 0) {
    float bb0 = b0[nA], bb1 = b0[nA + 1];
    float v00 = fmaxf(acc00 + bb0, 0.0f), v01 = fmaxf(acc01 + bb1, 0.0f);
    float v10 = fmaxf(acc10 + bb0, 0.0f), v11 = fmaxf(acc11 + bb1, 0.0f);
    Cout[mA * 512 + nA] = v00;       Cout[mA * 512 + nA + 1] = v01;
    Cout[(mA + 1) * 512 + nA] = v10; Cout[(mA + 1) * 512 + nA + 1] = v11;
    STATS(v00, v01, v10, v11, n0, 512);
  } else if constexpr (EPI == 1) {
    float bb0 = (n0 < 256) ? b0[nA] : b1[nA - 256];
    float bb1 = (n0 < 256) ? b0[nA + 1] : b1[nA + 1 - 256];
    float v00 = acc00 + bb0, v01 = acc01 + bb1;
    float v10 = acc10 + bb0, v11 = acc11 + bb1;
    if (n0 < 256) {
      muT[((t - 1) * NB + mA) * NH + nA] = v00;
      muT[((t - 1) * NB + mA) * NH + nA + 1] = v01;
      muT[((t - 1) * NB + mA + 1) * NH + nA] = v10;
      muT[((t - 1) * NB + mA + 1) * NH + nA + 1] = v11;
      outp[MUO_OFF + (mA * NT + t) * NH + nA] = v00;
      outp[MUO_OFF + (mA * NT + t) * NH + nA + 1] = v01;
      outp[MUO_OFF + ((mA + 1) * NT + t) * NH + nA] = v10;
      outp[MUO_OFF + ((mA + 1) * NT + t) * NH + nA + 1] = v11;
    } else {
      v00 = (v00 > 0.0f ? v00 : expm1f(v00)) + 1.0f + 1e-12f;
      v01 = (v01 > 0.0f ? v01 : expm1f(v01)) + 1.0f + 1e-12f;
      v10 = (v10 > 0.0f ? v10 : expm1f(v10)) + 1.0f + 1e-12f;
      v11 = (v11 > 0.0f ? v11 : expm1f(v11)) + 1.0f + 1e-12f;
      Cout[mA * 256 + (nA - 256)] = v00;       Cout[mA * 256 + (nA + 1 - 256)] = v01;
      Cout[(mA + 1) * 256 + (nA - 256)] = v10; Cout[(mA + 1) * 256 + (nA + 1 - 256)] = v11;
      STATS(v00, v01, v10, v11, n0 - 256, 256);
    }
  } else {
    float bb0 = (n0 < 128) ? b0[nA] : b1[nA - 128];
    float bb1 = (n0 < 128) ? b0[nA + 1] : b1[nA + 1 - 128];
    float v00 = acc00 + bb0, v01 = acc01 + bb1;
    float v10 = acc10 + bb0, v11 = acc11 + bb1;
    if (n0 >= 128) {
      v00 = (v00 > 0.0f ? v00 : expm1f(v00)) + 1.0f + 1e-12f;
      v01 = (v01 > 0.0f ? v01 : expm1f(v01)) + 1.0f + 1e-12f;
      v10 = (v10 > 0.0f ? v10 : expm1f(v10)) + 1.0f + 1e-12f;
      v11 = (v11 > 0.0f ? v11 : expm1f(v11)) + 1.0f + 1e-12f;
    }
    Cout[mA * 256 + nA] = v00;       Cout[mA * 256 + nA + 1] = v01;
    Cout[(mA + 1) * 256 + nA] = v10; Cout[(mA + 1) * 256 + nA + 1] = v11;
  }
}

// stats finalize for sd + BN-apply + write sdT/out
__global__ __launch_bounds__(256) void k_sdfin(
    const float* __restrict__ partS, const float* __restrict__ ps,
    const float* __restrict__ gs, const float* __restrict__ bes,
    float* __restrict__ sdT, float* __restrict__ outp, int t)
{
  int b = blockIdx.x;
  int c = threadIdx.x;
  float s = 0.0f, q = 0.0f;
  #pragma unroll
  for (int p = 0; p < 16; ++p) {
    s += partS[(p * 256 + c) * 2];
    q += partS[(p * 256 + c) * 2 + 1];
  }
  float mn  = s * (1.0f / 512.0f);
  float var = q * (1.0f / 512.0f) - mn * mn;
  float inv = 1.0f / sqrtf(var + 1e-5f);
  float sc  = inv * gs[c];
  float sh  = bes[c] - mn * sc;
  float v = ps[b * 256 + c] * sc + sh;
  sdT[((t - 1) * NB + b) * NH + c] = v;
  outp[VARO_OFF + (b * NT + t) * NH + c] = v;
}

// fused categorical + reparameterized ht
__global__ void k_pisht(const float* __restrict__ h_gru, int t,
                        uint32_t k1a, uint32_t k1b, uint32_t k2a, uint32_t k2b,
                        const float* __restrict__ muT, const float* __restrict__ sdT,
                        float* __restrict__ hstate)
{
  int b = blockIdx.x;
  int l = threadIdx.x;
  float v = -__builtin_inff();
  int idx = 0x7FFFFFFF;
  if (l < t) {
    const float* hq = h_gru + (b * NT + t) * NH;
    const float* hu = h_gru + (b * NT + l) * NH;
    float d = 0.0f;
    for (int h = 0; h < NH; ++h) d += hq[h] * hu[h];
    float logit = d * 0.0625f;
    uint32_t bits = rbits(k1a, k1b, (uint32_t)(b * t + l));
    float f = __fsub_rn(__uint_as_float((bits >> 9) | 0x3F800000u), 1.0f);
    const float tinyf = 1.1754943508222875e-38f;
    float u = fmaxf(tinyf, __fadd_rn(f, tinyf));
    float gmb = -logf(-logf(u));
    v = gmb + logit;
    idx = l;
  }
  for (int off = 32; off; off >>= 1) {
    float ov = __shfl_xor(v, off);
    int oi = __shfl_xor(idx, off);
    if (ov > v || (ov == v && oi < idx)) { v = ov; idx = oi; }
  }
  int p = idx;  // all lanes converged
  for (int h = l; h < NH; h += 64) {
    float mu = muT[(p * NB + b) * NH + h];
    float sd = sdT[(p * NB + b) * NH + h];
    float z = jax_normal(rbits(k2a, k2b, (uint32_t)(b * NH + h)));
    hstate[b * NH + h] = __fadd_rn(mu, __fmul_rn(sd, z));
  }
}

// emission sample: out = mean + std * z
__global__ __launch_bounds__(256) void k_sample(
    const float* __restrict__ tmp, uint32_t ka, uint32_t kb,
    float* __restrict__ outp, int t)
{
  int i = blockIdx.x * 256 + threadIdx.x;
  int b = i >> 7, j = i & 127;
  float mean = tmp[b * 256 + j];
  float stdv = tmp[b * 256 + 128 + j];
  float z = jax_normal(rbits(ka, kb, (uint32_t)(b * NO + j)));
  outp[(b * NT + t) * NO + j] = __fadd_rn(mean, __fmul_rn(stdv, z));
}

// ---------------- host ----------------

extern "C" void kernel_launch(void* const* d_in, const int* in_sizes, int n_in,
                              void* d_out, int out_size, void* d_ws, size_t ws_size,
                              hipStream_t stream)
{
  const float* x     = (const float*)d_in[0];
  const float* s     = (const float*)d_in[1];
  const float* h_gru = (const float*)d_in[2];
  const float* mu0   = (const float*)d_in[3];
  const float* var0  = (const float*)d_in[4];
  const float* h0    = (const float*)d_in[5];
  const float* tW1   = (const float*)d_in[6];
  const float* tb1   = (const float*)d_in[7];
  const float* tg1   = (const float*)d_in[8];
  const float* tbe1  = (const float*)d_in[9];
  const float* tW2   = (const float*)d_in[10];
  const float* tb2   = (const float*)d_in[11];
  const float* tg2   = (const float*)d_in[12];
  const float* tbe2  = (const float*)d_in[13];
  const float* tWm   = (const float*)d_in[14];
  const float* tbm   = (const float*)d_in[15];
  const float* tWs   = (const float*)d_in[16];
  const float* tbs   = (const float*)d_in[17];
  const float* tgs   = (const float*)d_in[18];
  const float* tbes  = (const float*)d_in[19];
  const float* eW1   = (const float*)d_in[20];
  const float* eb1   = (const float*)d_in[21];
  const float* eg1   = (const float*)d_in[22];
  const float* ebe1  = (const float*)d_in[23];
  const float* eWm   = (const float*)d_in[24];
  const float* ebm   = (const float*)d_in[25];
  const float* eWs   = (const float*)d_in[26];
  const float* ebs   = (const float*)d_in[27];

  float* out = (float*)d_out;
  float* ws = (float*)d_ws;

  float* muT    = ws;                        // 19*512*256
  float* sdT    = muT + 19 * NB * NH;        // 19*512*256
  float* hstate = sdT + 19 * NB * NH;        // 512*256
  float* a1     = hstate + NB * NH;          // 512*512
  float* a2     = a1 + NB * 512;             // 512*512
  float* ps     = a2 + NB * 512;             // 512*256
  float* e1     = ps + NB * NH;              // 512*512
  float* tmp    = e1 + NB * 512;             // 512*256
  float* part1  = tmp + NB * 256;            // 16*512*2
  float* part2  = part1 + 16 * 512 * 2;      // 16*512*2
  float* partS  = part2 + 16 * 512 * 2;      // 16*256*2
  float* partE  = partS + 16 * 256 * 2;      // 16*512*2

  dim3 g16(16, 16), g8(8, 16);

  k_init_x<<<(NB * NT * NO + 255) / 256, 256, 0, stream>>>(x, out);
  k_init_h<<<(NB * NH + 255) / 256, 256, 0, stream>>>(mu0, var0, h0, out, hstate);

  for (int t = 1; t < NT; ++t) {
    uint32_t kt0, kt1;
    tf2x32(0u, 42u, 0u, (uint32_t)t, kt0, kt1);         // fold_in(key(42), t)
    uint32_t k1a, k1b, k2a, k2b, k3a, k3b;
    tf2x32(kt0, kt1, 0u, 0u, k1a, k1b);                 // foldlike split
    tf2x32(kt0, kt1, 0u, 1u, k2a, k2b);
    tf2x32(kt0, kt1, 0u, 2u, k3a, k3b);

    // transition
    k_gemm<256, 0, 0, 0><<<g16, 256, 0, stream>>>(
        hstate, nullptr, nullptr, nullptr, nullptr,
        tW1, nullptr, tb1, nullptr, a1, part1, nullptr, nullptr, t);
    k_gemm<576, 1, 1, 0><<<g16, 256, 0, stream>>>(
        a1, s, part1, tg1, tbe1,
        tW2, nullptr, tb2, nullptr, a2, part2, nullptr, nullptr, t);
    k_gemm<512, 1, 0, 1><<<g16, 256, 0, stream>>>(
        a2, nullptr, part2, tg2, tbe2,
        tWm, tWs, tbm, tbs, ps, partS, muT, out, t);
    k_sdfin<<<NB, 256, 0, stream>>>(partS, ps, tgs, tbes, sdT, out, t);
    // sampling
    k_pisht<<<NB, 64, 0, stream>>>(h_gru, t, k1a, k1b, k2a, k2b, muT, sdT, hstate);
    // emission
    k_gemm<256, 0, 0, 0><<<g16, 256, 0, stream>>>(
        hstate, nullptr, nullptr, nullptr, nullptr,
        eW1, nullptr, eb1, nullptr, e1, partE, nullptr, nullptr, t);
    k_gemm<512, 1, 0, 2><<<g8, 256, 0, stream>>>(
        e1, nullptr, partE, eg1, ebe1,
        eWm, eWs, ebm, ebs, tmp, nullptr, nullptr, nullptr, t);
    k_sample<<<NB * NO / 256, 256, 0, stream>>>(tmp, k3a, k3b, out, t);
  }
}